// Round 5
// baseline (131.730 us; speedup 1.0000x reference)
//
#include <hip/hip_runtime.h>

// WaveletLayer on [4096,4096] fp32:
//   out = diag_s * DWT3( diag_g * (DWT3(diag_b * x))[perm] )
// Haar DWT3 packet layout: [cA3(512) | cD3(512) | cD2(1024) | cD1(2048)].
//
// R5 structure: 256 threads x R=4 rows/block. Row-invariant tables
// (diag_b, diag_g, perm) register-cached once per block. DWTs fully in
// registers (thread owns 16 contiguous columns). LDS only for the
// permutation round-trip: single 16 KB buffer, 2 barriers/row.
// KEY CHANGE vs R4: next row's x is prefetched into registers BEFORE the
// scatter/barrier/gather phase of the current row, so global-load latency
// overlaps the LDS phase (kernel was latency-bound: all pipes <36%).

#define D   4096
#define NT  256            // 16 columns / thread
#define R   4              // rows per block

#define C_INV_SQRT2 0.70710678118654752440f

typedef float vf2 __attribute__((ext_vector_type(2)));
typedef float vf4 __attribute__((ext_vector_type(4)));

// XOR swizzle to break power-of-2 patterns on the scatter writes.
static __device__ __forceinline__ int swz(int i) {
    return i ^ ((i >> 5) & 31);
}

// 3 in-register Haar levels on 16 contiguous elements.
static __device__ __forceinline__ void dwt3_reg(const float v[16],
                                                float a3[2], float d3[2],
                                                float d2[4], float d1[8]) {
    float a1[8];
    #pragma unroll
    for (int j = 0; j < 8; ++j) {
        a1[j] = (v[2 * j] + v[2 * j + 1]) * C_INV_SQRT2;
        d1[j] = (v[2 * j] - v[2 * j + 1]) * C_INV_SQRT2;
    }
    float a2[4];
    #pragma unroll
    for (int j = 0; j < 4; ++j) {
        a2[j] = (a1[2 * j] + a1[2 * j + 1]) * C_INV_SQRT2;
        d2[j] = (a1[2 * j] - a1[2 * j + 1]) * C_INV_SQRT2;
    }
    #pragma unroll
    for (int j = 0; j < 2; ++j) {
        a3[j] = (a2[2 * j] + a2[2 * j + 1]) * C_INV_SQRT2;
        d3[j] = (a2[2 * j] - a2[2 * j + 1]) * C_INV_SQRT2;
    }
}

__global__ __launch_bounds__(NT) void wavelet_rows_kernel(
    const float* __restrict__ x,
    const float* __restrict__ diag_s,
    const float* __restrict__ diag_g,
    const float* __restrict__ diag_b,
    const int*   __restrict__ perm,
    float*       __restrict__ out)
{
    __shared__ float buf[D];   // single buffer; 2 barriers/row

    const int t = threadIdx.x;
    const size_t row0 = (size_t)blockIdx.x * R;

    // ---- register-cache row-invariant tables (once per block) ----
    float db[16], dg[16];
    int   pidx[16];
    {
        const vf4* b4 = (const vf4*)diag_b;
        const vf4* g4 = (const vf4*)diag_g;
        const int4* p4 = (const int4*)perm;
        #pragma unroll
        for (int k = 0; k < 4; ++k) {
            vf4 bv = b4[4 * t + k];
            db[4 * k + 0] = bv.x; db[4 * k + 1] = bv.y;
            db[4 * k + 2] = bv.z; db[4 * k + 3] = bv.w;
            vf4 gv = g4[4 * t + k];
            dg[4 * k + 0] = gv.x; dg[4 * k + 1] = gv.y;
            dg[4 * k + 2] = gv.z; dg[4 * k + 3] = gv.w;
            int4 pv = p4[4 * t + k];
            pidx[4 * k + 0] = pv.x; pidx[4 * k + 1] = pv.y;
            pidx[4 * k + 2] = pv.z; pidx[4 * k + 3] = pv.w;
        }
    }

    // ---- prologue: load row 0's x ----
    vf4 xv[4];
    {
        const vf4* x4 = (const vf4*)(x + row0 * (size_t)D);
        #pragma unroll
        for (int k = 0; k < 4; ++k) xv[k] = x4[4 * t + k];
    }

    // ---- row loop, software-pipelined on the x load ----
    for (int r = 0; r < R; ++r) {
        // consume current row's x * diag_b
        float v[16];
        #pragma unroll
        for (int k = 0; k < 4; ++k) {
            v[4 * k + 0] = xv[k].x * db[4 * k + 0];
            v[4 * k + 1] = xv[k].y * db[4 * k + 1];
            v[4 * k + 2] = xv[k].z * db[4 * k + 2];
            v[4 * k + 3] = xv[k].w * db[4 * k + 3];
        }

        // prefetch next row's x — in flight across the whole LDS phase
        if (r + 1 < R) {
            const vf4* xn = (const vf4*)(x + (row0 + r + 1) * (size_t)D);
            #pragma unroll
            for (int k = 0; k < 4; ++k) xv[k] = xn[4 * t + k];
        }

        // DWT #1 in registers
        float a3[2], d3[2], d2[4], d1[8];
        dwt3_reg(v, a3, d3, d2, d1);

        // scatter packet layout to LDS (swizzled)
        #pragma unroll
        for (int j = 0; j < 2; ++j) buf[swz(2 * t + j)]        = a3[j];
        #pragma unroll
        for (int j = 0; j < 2; ++j) buf[swz(512 + 2 * t + j)]  = d3[j];
        #pragma unroll
        for (int j = 0; j < 4; ++j) buf[swz(1024 + 4 * t + j)] = d2[j];
        #pragma unroll
        for (int j = 0; j < 8; ++j) buf[swz(2048 + 8 * t + j)] = d1[j];

        __syncthreads();

        // permutation gather * diag_g
        float w[16];
        #pragma unroll
        for (int k = 0; k < 16; ++k) {
            w[k] = buf[swz(pidx[k])] * dg[k];
        }

        __syncthreads();   // buf safe for next row's scatter

        // DWT #2 in registers
        float b3[2], e3[2], e2[4], e1[8];
        dwt3_reg(w, b3, e3, e2, e1);

        // multiply diag_s (reloaded per row; L1-resident) and store
        float* orow = out + (row0 + r) * (size_t)D;
        {
            const vf2* s2 = (const vf2*)diag_s;
            vf2* o2 = (vf2*)orow;
            vf2 sv, ov;
            sv = s2[t];                   // cA3: floats 2t,2t+1
            ov.x = b3[0] * sv.x; ov.y = b3[1] * sv.y;
            o2[t] = ov;
            sv = s2[256 + t];             // cD3
            ov.x = e3[0] * sv.x; ov.y = e3[1] * sv.y;
            o2[256 + t] = ov;

            const vf4* s4 = (const vf4*)diag_s;
            vf4* o4 = (vf4*)orow;
            vf4 sw, o;
            sw = s4[256 + t];             // cD2
            o.x = e2[0] * sw.x; o.y = e2[1] * sw.y;
            o.z = e2[2] * sw.z; o.w = e2[3] * sw.w;
            o4[256 + t] = o;
            sw = s4[512 + 2 * t];         // cD1 lo
            o.x = e1[0] * sw.x; o.y = e1[1] * sw.y;
            o.z = e1[2] * sw.z; o.w = e1[3] * sw.w;
            o4[512 + 2 * t] = o;
            sw = s4[512 + 2 * t + 1];     // cD1 hi
            o.x = e1[4] * sw.x; o.y = e1[5] * sw.y;
            o.z = e1[6] * sw.z; o.w = e1[7] * sw.w;
            o4[512 + 2 * t + 1] = o;
        }
    }
}

extern "C" void kernel_launch(void* const* d_in, const int* in_sizes, int n_in,
                              void* d_out, int out_size, void* d_ws, size_t ws_size,
                              hipStream_t stream) {
    // setup_inputs() order: x, diag_s, diag_g, diag_b, dec_lo, dec_hi, perm, scales
    const float* x      = (const float*)d_in[0];
    const float* diag_s = (const float*)d_in[1];
    const float* diag_g = (const float*)d_in[2];
    const float* diag_b = (const float*)d_in[3];
    const int* perm     = (const int*)d_in[6];
    float* out          = (float*)d_out;

    const int B = 4096 / R;
    wavelet_rows_kernel<<<B, NT, 0, stream>>>(x, diag_s, diag_g, diag_b, perm, out);
}

// Round 6
// 131.327 us; speedup vs baseline: 1.0031x; 1.0031x over previous
//
#include <hip/hip_runtime.h>

// WaveletLayer on [4096,4096] fp32:
//   out = diag_s * DWT3( diag_g * (DWT3(diag_b * x))[perm] )
// Haar DWT3 packet layout: [cA3(512) | cD3(512) | cD2(1024) | cD1(2048)].
//
// R6 structure: 256 threads, R=4 rows/block, thread owns 16 contiguous
// columns of all 4 rows. DWTs fully in registers. The permutation LDS
// round-trip is VECTORIZED ACROSS ROWS: coefficient position p is stored as
// a 16B block {row0..row3} (ds_write_b128), and one random ds_read_b128 at
// perm[k] serves all 4 rows. 16 writes + 16 reads + 1 barrier per BLOCK
// (was 64+64+8 per block in R5). Block index XOR-swizzled for bank spread.

#define D   4096
#define NT  256            // 16 columns / thread
#define R   4              // rows per block

#define C_INV_SQRT2 0.70710678118654752440f

typedef float vf2 __attribute__((ext_vector_type(2)));
typedef float vf4 __attribute__((ext_vector_type(4)));

// block-index swizzle: spreads 16B-block positions across all 8 bank-spans
static __device__ __forceinline__ int swzB(int p) {
    return p ^ ((p >> 3) & 7);
}

// 3 in-register Haar levels on 16 contiguous elements.
// Output packed as c[0..1]=cA3(@2t), c[2..3]=cD3(@512+2t),
// c[4..7]=cD2(@1024+4t), c[8..15]=cD1(@2048+8t).
static __device__ __forceinline__ void dwt3_reg(const float v[16], float c[16]) {
    float a1[8];
    #pragma unroll
    for (int j = 0; j < 8; ++j) {
        a1[j]     = (v[2 * j] + v[2 * j + 1]) * C_INV_SQRT2;
        c[8 + j]  = (v[2 * j] - v[2 * j + 1]) * C_INV_SQRT2;   // d1
    }
    float a2[4];
    #pragma unroll
    for (int j = 0; j < 4; ++j) {
        a2[j]    = (a1[2 * j] + a1[2 * j + 1]) * C_INV_SQRT2;
        c[4 + j] = (a1[2 * j] - a1[2 * j + 1]) * C_INV_SQRT2;  // d2
    }
    #pragma unroll
    for (int j = 0; j < 2; ++j) {
        c[j]     = (a2[2 * j] + a2[2 * j + 1]) * C_INV_SQRT2;  // a3
        c[2 + j] = (a2[2 * j] - a2[2 * j + 1]) * C_INV_SQRT2;  // d3
    }
}

__global__ __launch_bounds__(NT) void wavelet_rows_kernel(
    const float* __restrict__ x,
    const float* __restrict__ diag_s,
    const float* __restrict__ diag_g,
    const float* __restrict__ diag_b,
    const int*   __restrict__ perm,
    float*       __restrict__ out)
{
    __shared__ vf4 lds4[D];    // 64 KB: [coef position][row 0..3]

    const int t = threadIdx.x;
    const size_t row0 = (size_t)blockIdx.x * R;

    // ---- register-cache row-invariant tables (once per block) ----
    float db[16], dg[16];
    int   pidx[16];
    {
        const vf4* b4 = (const vf4*)diag_b;
        const vf4* g4 = (const vf4*)diag_g;
        const int4* p4 = (const int4*)perm;
        #pragma unroll
        for (int k = 0; k < 4; ++k) {
            vf4 bv = b4[4 * t + k];
            db[4 * k + 0] = bv.x; db[4 * k + 1] = bv.y;
            db[4 * k + 2] = bv.z; db[4 * k + 3] = bv.w;
            vf4 gv = g4[4 * t + k];
            dg[4 * k + 0] = gv.x; dg[4 * k + 1] = gv.y;
            dg[4 * k + 2] = gv.z; dg[4 * k + 3] = gv.w;
            int4 pv = p4[4 * t + k];
            pidx[4 * k + 0] = pv.x; pidx[4 * k + 1] = pv.y;
            pidx[4 * k + 2] = pv.z; pidx[4 * k + 3] = pv.w;
        }
    }

    // thread-owned packet positions for the scatter
    int pos[16];
    #pragma unroll
    for (int j = 0; j < 2; ++j) pos[j]     = 2 * t + j;
    #pragma unroll
    for (int j = 0; j < 2; ++j) pos[2 + j] = 512 + 2 * t + j;
    #pragma unroll
    for (int j = 0; j < 4; ++j) pos[4 + j] = 1024 + 4 * t + j;
    #pragma unroll
    for (int j = 0; j < 8; ++j) pos[8 + j] = 2048 + 8 * t + j;

    // ---- load all 4 rows' x (64 independent-16B loads in flight) ----
    vf4 xv[R][4];
    #pragma unroll
    for (int r = 0; r < R; ++r) {
        const vf4* x4 = (const vf4*)(x + (row0 + r) * (size_t)D);
        #pragma unroll
        for (int k = 0; k < 4; ++k) xv[r][k] = x4[4 * t + k];
    }

    // ---- DWT #1 per row, fully in registers ----
    float cf[R][16];
    #pragma unroll
    for (int r = 0; r < R; ++r) {
        float v[16];
        #pragma unroll
        for (int k = 0; k < 4; ++k) {
            v[4 * k + 0] = xv[r][k].x * db[4 * k + 0];
            v[4 * k + 1] = xv[r][k].y * db[4 * k + 1];
            v[4 * k + 2] = xv[r][k].z * db[4 * k + 2];
            v[4 * k + 3] = xv[r][k].w * db[4 * k + 3];
        }
        dwt3_reg(v, cf[r]);
    }

    // ---- scatter: one b128 per coefficient position (all 4 rows) ----
    #pragma unroll
    for (int k = 0; k < 16; ++k) {
        vf4 c4;
        c4.x = cf[0][k]; c4.y = cf[1][k];
        c4.z = cf[2][k]; c4.w = cf[3][k];
        lds4[swzB(pos[k])] = c4;
    }

    __syncthreads();   // the only barrier

    // ---- gather: one random b128 per perm index serves all 4 rows ----
    float w[R][16];
    #pragma unroll
    for (int k = 0; k < 16; ++k) {
        vf4 f = lds4[swzB(pidx[k])];
        w[0][k] = f.x * dg[k];
        w[1][k] = f.y * dg[k];
        w[2][k] = f.z * dg[k];
        w[3][k] = f.w * dg[k];
    }

    // ---- DWT #2 per row + diag_s + store ----
    const vf2* s2 = (const vf2*)diag_s;
    const vf4* s4 = (const vf4*)diag_s;
    const vf2 sA   = s2[t];
    const vf2 sD3  = s2[256 + t];
    const vf4 sD2  = s4[256 + t];
    const vf4 sD1a = s4[512 + 2 * t];
    const vf4 sD1b = s4[512 + 2 * t + 1];

    #pragma unroll
    for (int r = 0; r < R; ++r) {
        float e[16];
        dwt3_reg(w[r], e);

        float* orow = out + (row0 + r) * (size_t)D;
        vf2* o2 = (vf2*)orow;
        vf4* o4 = (vf4*)orow;
        vf2 ov;
        ov.x = e[0] * sA.x;  ov.y = e[1] * sA.y;
        o2[t] = ov;                       // cA3
        ov.x = e[2] * sD3.x; ov.y = e[3] * sD3.y;
        o2[256 + t] = ov;                 // cD3
        vf4 o;
        o.x = e[4] * sD2.x; o.y = e[5] * sD2.y;
        o.z = e[6] * sD2.z; o.w = e[7] * sD2.w;
        o4[256 + t] = o;                  // cD2
        o.x = e[8]  * sD1a.x; o.y = e[9]  * sD1a.y;
        o.z = e[10] * sD1a.z; o.w = e[11] * sD1a.w;
        o4[512 + 2 * t] = o;              // cD1 lo
        o.x = e[12] * sD1b.x; o.y = e[13] * sD1b.y;
        o.z = e[14] * sD1b.z; o.w = e[15] * sD1b.w;
        o4[512 + 2 * t + 1] = o;          // cD1 hi
    }
}

extern "C" void kernel_launch(void* const* d_in, const int* in_sizes, int n_in,
                              void* d_out, int out_size, void* d_ws, size_t ws_size,
                              hipStream_t stream) {
    // setup_inputs() order: x, diag_s, diag_g, diag_b, dec_lo, dec_hi, perm, scales
    const float* x      = (const float*)d_in[0];
    const float* diag_s = (const float*)d_in[1];
    const float* diag_g = (const float*)d_in[2];
    const float* diag_b = (const float*)d_in[3];
    const int* perm     = (const int*)d_in[6];
    float* out          = (float*)d_out;

    const int B = 4096 / R;
    wavelet_rows_kernel<<<B, NT, 0, stream>>>(x, diag_s, diag_g, diag_b, perm, out);
}